// Round 6
// baseline (191.065 us; speedup 1.0000x reference)
//
#include <hip/hip_runtime.h>
#include <hip/hip_bf16.h>

#define BROWS 32768
#define CDIM 1000
#define CPAD 1024
#define HDIM 128
#define REG 1056                     // PHYS(1023)+2 words, one padded region per wave
#define PHYS(i) ((i) + ((i) >> 5))   // +1 pad word per 32: kills 64B-stride bank aliasing

typedef __attribute__((ext_vector_type(8))) short short8;
typedef __attribute__((ext_vector_type(4))) float f32x4;

__device__ inline unsigned short f2bf(float x) {
    unsigned int b = __float_as_uint(x);
    unsigned int r = (b + 0x7FFFu + ((b >> 16) & 1u)) >> 16;  // RNE
    return (unsigned short)r;
}
__device__ inline float bf2f(unsigned short u) {
    return __uint_as_float(((unsigned int)u) << 16);
}

// ---------------- prep: transpose weights to [N][K] bf16, zero-padded ----------------
__global__ __launch_bounds__(256) void k_prep(const float* __restrict__ W1,
                                              const float* __restrict__ W2,
                                              const float* __restrict__ W3,
                                              unsigned short* __restrict__ W1t,
                                              unsigned short* __restrict__ W2t,
                                              unsigned short* __restrict__ W3t) {
    const int idx = blockIdx.x * 256 + threadIdx.x;  // [0, 131072)
    {   // W1t[n][k], n<128, k<1024 ; W1 is [1000][128]
        const int n = idx >> 10, k = idx & 1023;
        W1t[idx] = (k < CDIM) ? f2bf(W1[(size_t)k * HDIM + n]) : (unsigned short)0;
    }
    {   // W3t[n][k], n<1024, k<128 ; W3 is [128][1000]
        const int n = idx >> 7, k = idx & 127;
        W3t[idx] = (n < CDIM) ? f2bf(W3[(size_t)k * CDIM + n]) : (unsigned short)0;
    }
    if (idx < 16384) {  // W2t[n][k], 128x128 ; W2 is [128][128]
        const int n = idx >> 7, k = idx & 127;
        W2t[idx] = f2bf(W2[(size_t)k * HDIM + n]);
    }
}

// ---------------- row stats: one wave per row, write {max, 1/sum} (8B/row) -----------
__global__ __launch_bounds__(256) void k_rowstat(const float* __restrict__ logits,
                                                 float2* __restrict__ rstat) {
    const int wv = threadIdx.x >> 6, lane = threadIdx.x & 63;
    const int row = (blockIdx.x << 2) + wv;
    const int base = lane << 4;
    const float* lrow = logits + (size_t)row * CDIM;
    float lg[16];
#pragma unroll
    for (int q = 0; q < 4; ++q) {
        const int c = base + (q << 2);
        if (c < CDIM) {
            const float4 v4 = *reinterpret_cast<const float4*>(lrow + c);
            lg[q * 4] = v4.x; lg[q * 4 + 1] = v4.y; lg[q * 4 + 2] = v4.z; lg[q * 4 + 3] = v4.w;
        } else {
            lg[q * 4] = lg[q * 4 + 1] = lg[q * 4 + 2] = lg[q * 4 + 3] = -INFINITY;
        }
    }
    float mx = lg[0];
#pragma unroll
    for (int e = 1; e < 16; ++e) mx = fmaxf(mx, lg[e]);
#pragma unroll
    for (int off = 32; off >= 1; off >>= 1) mx = fmaxf(mx, __shfl_xor(mx, off));
    float s = 0.f;
#pragma unroll
    for (int e = 0; e < 16; ++e) s += __expf(lg[e] - mx);
#pragma unroll
    for (int off = 32; off >= 1; off >>= 1) s += __shfl_xor(s, off);
    if (lane == 0) rstat[row] = make_float2(mx, 1.f / s);
}

// ---------------- GEMM1 fused: h1 = relu(softmax(logits) @ W1 + b1) ------------------
// A-tile staged by computing exp(logit-mx)*inv -> bf16 on the fly (logits L3-warm
// after k_rowstat). 512 threads = 8 waves (4m x 2n), tile 128x128, BK=64.
__global__ __launch_bounds__(512) void k_gemm1f(const float* __restrict__ logits,
                                                const float2* __restrict__ rstat,
                                                const unsigned short* __restrict__ W1t,
                                                const float* __restrict__ b1,
                                                unsigned short* __restrict__ h1) {
    __shared__ uint4 As[128 * 8];
    __shared__ uint4 Bs[128 * 8];
    const int tid = threadIdx.x;
    const int bm = blockIdx.x;
    const int lane = tid & 63, w = tid >> 6;
    const int wm = (w >> 1) << 5;
    const int wn = (w & 1) << 6;
    const int l15 = lane & 15, l4 = lane >> 4;
    f32x4 acc[2][4] = {};

    const int r = tid >> 2, q4 = tid & 3;   // staging: row, 16-col quarter
    const float* lrowS = logits + (size_t)(bm * 128 + r) * CDIM;
    const float2 st = rstat[bm * 128 + r];
    const float mxv = st.x, invv = st.y;

    for (int k0 = 0; k0 < CPAD; k0 += 64) {
        __syncthreads();
        // stage A: exp-normalize 16 logits -> bf16, write 2 swizzled 16B chunks
        {
            unsigned int wd[8];
#pragma unroll
            for (int j = 0; j < 4; ++j) {
                const int c = k0 + (q4 << 4) + (j << 2);
                float p0 = 0.f, p1 = 0.f, p2 = 0.f, p3 = 0.f;
                if (c < CDIM) {   // CDIM % 4 == 0: float4 fully valid or fully pad
                    const float4 v4 = *reinterpret_cast<const float4*>(lrowS + c);
                    p0 = __expf(v4.x - mxv) * invv;
                    p1 = __expf(v4.y - mxv) * invv;
                    p2 = __expf(v4.z - mxv) * invv;
                    p3 = __expf(v4.w - mxv) * invv;
                }
                wd[2 * j]     = (unsigned int)f2bf(p0) | ((unsigned int)f2bf(p1) << 16);
                wd[2 * j + 1] = (unsigned int)f2bf(p2) | ((unsigned int)f2bf(p3) << 16);
            }
            const int cc = q4 << 1;
            uint4 u0, u1;
            u0.x = wd[0]; u0.y = wd[1]; u0.z = wd[2]; u0.w = wd[3];
            u1.x = wd[4]; u1.y = wd[5]; u1.z = wd[6]; u1.w = wd[7];
            As[(r << 3) + (cc ^ (r & 7))] = u0;
            As[(r << 3) + ((cc + 1) ^ (r & 7))] = u1;
        }
        // stage B (W1t), 2 chunks/thread
#pragma unroll
        for (int i = 0; i < 2; ++i) {
            const int cid = tid + (i << 9);
            const int rb = cid >> 3, cb = cid & 7;
            Bs[(rb << 3) + (cb ^ (rb & 7))] =
                *reinterpret_cast<const uint4*>(W1t + (size_t)rb * CPAD + k0 + (cb << 3));
        }
        __syncthreads();
#pragma unroll
        for (int kk = 0; kk < 2; ++kk) {
            short8 a[2], b[4];
#pragma unroll
            for (int mf = 0; mf < 2; ++mf) {
                const int rr = wm + (mf << 4) + l15;
                a[mf] = *reinterpret_cast<const short8*>(&As[(rr << 3) + (((kk << 2) + l4) ^ (rr & 7))]);
            }
#pragma unroll
            for (int nf = 0; nf < 4; ++nf) {
                const int rr = wn + (nf << 4) + l15;
                b[nf] = *reinterpret_cast<const short8*>(&Bs[(rr << 3) + (((kk << 2) + l4) ^ (rr & 7))]);
            }
#pragma unroll
            for (int mf = 0; mf < 2; ++mf)
#pragma unroll
                for (int nf = 0; nf < 4; ++nf)
                    acc[mf][nf] = __builtin_amdgcn_mfma_f32_16x16x32_bf16(a[mf], b[nf], acc[mf][nf], 0, 0, 0);
        }
    }
#pragma unroll
    for (int mf = 0; mf < 2; ++mf) {
#pragma unroll
        for (int nf = 0; nf < 4; ++nf) {
            const int n = wn + (nf << 4) + l15;
            const float bv = b1[n];
#pragma unroll
            for (int rr = 0; rr < 4; ++rr) {
                const int m = (bm << 7) + wm + (mf << 4) + (l4 << 2) + rr;
                h1[(size_t)m * HDIM + n] = f2bf(fmaxf(acc[mf][nf][rr] + bv, 0.f));
            }
        }
    }
}

// ---------------- GEMM: C[M,N] = epi(A[M,K] @ Bt[N,K]^T + bias) ----------------------
// EPI 0: relu(v + bias), all cols. EPI 1: sigmoid(v+bias) except col nlimit-1 raw;
//        stores only n < nlimit (compact ldo).
template <int EPI>
__global__ __launch_bounds__(512) void k_gemm(const unsigned short* __restrict__ A, int lda,
                                              const unsigned short* __restrict__ Bt, int ldb,
                                              const float* __restrict__ bias,
                                              unsigned short* __restrict__ outp, int ldo,
                                              int K, int nlimit) {
    __shared__ uint4 As[128 * 8];
    __shared__ uint4 Bs[128 * 8];
    const int tid = threadIdx.x;
    const int bm = blockIdx.x, bn = blockIdx.y;
    const int lane = tid & 63, w = tid >> 6;
    const int wm = (w >> 1) << 5;
    const int wn = (w & 1) << 6;
    const int l15 = lane & 15, l4 = lane >> 4;
    f32x4 acc[2][4] = {};

    for (int k0 = 0; k0 < K; k0 += 64) {
        __syncthreads();
#pragma unroll
        for (int i = 0; i < 2; ++i) {
            const int cid = tid + (i << 9);
            const int r = cid >> 3, c = cid & 7;
            As[(r << 3) + (c ^ (r & 7))] =
                *reinterpret_cast<const uint4*>(A + (size_t)(bm * 128 + r) * lda + k0 + (c << 3));
            Bs[(r << 3) + (c ^ (r & 7))] =
                *reinterpret_cast<const uint4*>(Bt + (size_t)(bn * 128 + r) * ldb + k0 + (c << 3));
        }
        __syncthreads();
#pragma unroll
        for (int kk = 0; kk < 2; ++kk) {
            short8 a[2], b[4];
#pragma unroll
            for (int mf = 0; mf < 2; ++mf) {
                const int r = wm + (mf << 4) + l15;
                a[mf] = *reinterpret_cast<const short8*>(&As[(r << 3) + (((kk << 2) + l4) ^ (r & 7))]);
            }
#pragma unroll
            for (int nf = 0; nf < 4; ++nf) {
                const int r = wn + (nf << 4) + l15;
                b[nf] = *reinterpret_cast<const short8*>(&Bs[(r << 3) + (((kk << 2) + l4) ^ (r & 7))]);
            }
#pragma unroll
            for (int mf = 0; mf < 2; ++mf)
#pragma unroll
                for (int nf = 0; nf < 4; ++nf)
                    acc[mf][nf] = __builtin_amdgcn_mfma_f32_16x16x32_bf16(a[mf], b[nf], acc[mf][nf], 0, 0, 0);
        }
    }
#pragma unroll
    for (int mf = 0; mf < 2; ++mf) {
#pragma unroll
        for (int nf = 0; nf < 4; ++nf) {
            const int n = (bn << 7) + wn + (nf << 4) + l15;
            if (EPI == 1 && n >= nlimit) continue;   // compact output: skip pad cols
            const float bv = bias[n];
#pragma unroll
            for (int r = 0; r < 4; ++r) {
                const int m = (bm << 7) + wm + (mf << 4) + (l4 << 2) + r;
                float v = acc[mf][nf][r] + bv;
                if (EPI == 0) {
                    v = fmaxf(v, 0.f);
                } else {
                    if (n != nlimit - 1) v = 1.f / (1.f + __expf(-v));
                }
                outp[(size_t)m * ldo + n] = f2bf(v);
            }
        }
    }
}

// ---------------- sort + finish: counting sort v5, one wave per row --------------------
// Single padded LDS region per wave (1056 words): hist -> start table -> sortedp ->
// Sarr, each phase overwriting the previous (dead) image; all in-order within wave,
// zero barriers. PHYS(i)=i+(i>>5) keeps every blocked access conflict-free.
// Softmax stats read from precomputed rstat (no reductions here).
__global__ __launch_bounds__(256) void k_sortfinish(const float* __restrict__ logits,
                                                    const float2* __restrict__ rstat,
                                                    const unsigned short* __restrict__ cal,
                                                    float* __restrict__ out) {
    __shared__ unsigned int shm[4 * REG];
    const int wv = threadIdx.x >> 6, lane = threadIdx.x & 63;
    const int row = (blockIdx.x << 2) + wv;
    unsigned int* smA = &shm[wv * REG];
    const int base = lane << 4;
    const int pb = base + (lane >> 1);   // PHYS(base + e) == pb + e for e in [0,16)

    // zero histogram images PHYS(0..1023)
#pragma unroll
    for (int e = 0; e < 16; ++e) smA[pb + e] = 0u;

    // ---- load logits + hoist cal row (cal compact: ldo = CDIM) ----
    const float* lrow = logits + (size_t)row * CDIM;
    float lg[16];
#pragma unroll
    for (int q = 0; q < 4; ++q) {
        const int c = base + (q << 2);
        if (c < CDIM) {
            const float4 v4 = *reinterpret_cast<const float4*>(lrow + c);
            lg[q * 4] = v4.x; lg[q * 4 + 1] = v4.y; lg[q * 4 + 2] = v4.z; lg[q * 4 + 3] = v4.w;
        } else {
            lg[q * 4] = lg[q * 4 + 1] = lg[q * 4 + 2] = lg[q * 4 + 3] = -INFINITY;
        }
    }
    const unsigned short* crow = cal + (size_t)row * CDIM + base;
    const uint4 c0v = *reinterpret_cast<const uint4*>(crow);       // overreads past 1000
    const uint4 c1v = *reinterpret_cast<const uint4*>(crow + 8);   // land in ws: safe, unused

    // ---- probs from precomputed stats (pads: exp(-inf)=0) ----
    const float2 st = rstat[row];
    const float mx = st.x, inv = st.y;
    float p[16];
#pragma unroll
    for (int e = 0; e < 16; ++e) p[e] = __expf(lg[e] - mx) * inv;

    // ---- single atomic pass: histogram count + stable in-bucket offset ----
    unsigned int key[16], offv[16];
#pragma unroll
    for (int e = 0; e < 16; ++e) {
        key[e] = __float_as_uint(p[e]) >> 20;   // 11-bit monotone key, <= 1016
        offv[e] = (base + e < CDIM) ? atomicAdd(&smA[PHYS(key[e])], 1u) : 0u;
    }

    // ---- bucket suffix-scan: start[b] = sum_{b' > b} cnt[b'] ----
    {
        unsigned int c16[16];
#pragma unroll
        for (int e = 0; e < 16; ++e) c16[e] = smA[pb + e];
        unsigned int lsum = 0;
#pragma unroll
        for (int e = 0; e < 16; ++e) lsum += c16[e];
        unsigned int suf = lsum;
#pragma unroll
        for (int off = 1; off < 64; off <<= 1) {
            const unsigned int u = __shfl_down(suf, off);
            if (lane + off < 64) suf += u;
        }
        unsigned int run = suf - lsum;
        unsigned int stv[16];
#pragma unroll
        for (int e = 15; e >= 0; --e) { stv[e] = run; run += c16[e]; }
#pragma unroll
        for (int e = 0; e < 16; ++e) smA[pb + e] = stv[e];
    }

    // ---- rank = start[key] + offset ----
    int rk[16];
#pragma unroll
    for (int e = 0; e < 16; ++e)
        rk[e] = (base + e < CDIM) ? (int)(smA[PHYS(key[e])] + offv[e]) : 1023;

    // ---- scatter probs to rank order (start table dead) ----
#pragma unroll
    for (int e = 0; e < 16; ++e)
        if (base + e < CDIM) smA[PHYS(rk[e])] = __float_as_uint(p[e]);

    // ---- rank-space diffs * cal ----
    float sp[16];
#pragma unroll
    for (int e = 0; e < 16; ++e) sp[e] = __uint_as_float(smA[pb + e]);
    const float spn_next = __shfl_down(sp[0], 1);
    const unsigned int cw[8] = {c0v.x, c0v.y, c0v.z, c0v.w, c1v.x, c1v.y, c1v.z, c1v.w};
    float v[16];
#pragma unroll
    for (int e = 0; e < 16; ++e) {
        const int r = base + e;
        const float cv = bf2f((unsigned short)((cw[e >> 1] >> ((e & 1) * 16)) & 0xFFFFu));
        const float spn = (e < 15) ? sp[e + 1] : spn_next;
        float val;
        if (r < CDIM - 1) val = (sp[e] - spn) * cv;
        else if (r == CDIM - 1) val = cv;
        else val = 0.f;
        v[e] = val;
    }
    // suffix sum over rank space
    float lsuf[16], run = 0.f;
#pragma unroll
    for (int e = 15; e >= 0; --e) { run += v[e]; lsuf[e] = run; }
    float pi = run;
#pragma unroll
    for (int off = 1; off < 64; off <<= 1) {
        const float u = __shfl_up(pi, off);
        if (lane >= off) pi += u;
    }
    const float tot = __shfl(pi, 63);
    const float after = tot - pi;

    // ---- Sarr overwrites sortedp (sp already in regs), gather by rank ----
#pragma unroll
    for (int e = 0; e < 16; ++e) smA[pb + e] = __float_as_uint(lsuf[e] + after);
    float f[16];
#pragma unroll
    for (int e = 0; e < 16; ++e) f[e] = __uint_as_float(smA[PHYS(rk[e])]);
#pragma unroll
    for (int q = 0; q < 4; ++q) {
        const int c = base + (q << 2);
        if (c < CDIM) {
            float4 o;
            o.x = lg[q * 4] + f[q * 4];
            o.y = lg[q * 4 + 1] + f[q * 4 + 1];
            o.z = lg[q * 4 + 2] + f[q * 4 + 2];
            o.w = lg[q * 4 + 3] + f[q * 4 + 3];
            *reinterpret_cast<float4*>(out + (size_t)row * CDIM + c) = o;
        }
    }
}

// ---------------- host ----------------
extern "C" void kernel_launch(void* const* d_in, const int* in_sizes, int n_in,
                              void* d_out, int out_size, void* d_ws, size_t ws_size,
                              hipStream_t stream) {
    const float* logits = (const float*)d_in[0];
    const float* W1 = (const float*)d_in[1];
    const float* b1 = (const float*)d_in[2];
    const float* W2 = (const float*)d_in[3];
    const float* b2 = (const float*)d_in[4];
    const float* W3 = (const float*)d_in[5];
    const float* b3 = (const float*)d_in[6];
    float* out = (float*)d_out;

    char* ws = (char*)d_ws;
    float2*         rstat = (float2*)ws;                           // 256 KB
    unsigned short* h1    = (unsigned short*)(ws + 262144);        // 8 MB
    unsigned short* h2    = (unsigned short*)(ws + 8650752);       // 8 MB
    unsigned short* cal   = (unsigned short*)(ws + 17039360);      // 62.5 MB (ldo=1000)
    unsigned short* W1t   = (unsigned short*)(ws + 82575360);      // 256 KB
    unsigned short* W2t   = (unsigned short*)(ws + 82837504);      // 32 KB
    unsigned short* W3t   = (unsigned short*)(ws + 82870272);      // 256 KB -> 83.1 MB total

    k_prep<<<512, 256, 0, stream>>>(W1, W2, W3, W1t, W2t, W3t);
    k_rowstat<<<BROWS / 4, 256, 0, stream>>>(logits, rstat);
    k_gemm1f<<<BROWS / 128, 512, 0, stream>>>(logits, rstat, W1t, b1, h1);
    k_gemm<0><<<dim3(BROWS / 128, 1), 512, 0, stream>>>(h1, HDIM, W2t, HDIM, b2, h2, HDIM, HDIM, 0);
    k_gemm<1><<<dim3(BROWS / 128, 8), 512, 0, stream>>>(h2, HDIM, W3t, HDIM, b3, cal, CDIM, HDIM, CDIM);
    k_sortfinish<<<BROWS / 4, 256, 0, stream>>>(logits, rstat, cal, out);
}

// Round 9
// 177.533 us; speedup vs baseline: 1.0762x; 1.0762x over previous
//
#include <hip/hip_runtime.h>
#include <hip/hip_bf16.h>

#define BROWS 32768
#define CDIM 1000
#define CPAD 1024
#define HDIM 128
// Bijective LDS word swizzle: XOR bits5-7 into bits2-4. Keeps aligned 4-word chunks
// contiguous (b128-able) and spreads the 64B-lane-stride blocked pattern across all
// 8 bank groups (balanced, 8cyc/b128 = floor). Random b32 accesses unaffected.
#define SWZ(w) ((w) ^ ((((w) >> 5) & 7) << 2))

typedef __attribute__((ext_vector_type(8))) short short8;
typedef __attribute__((ext_vector_type(4))) float f32x4;

__device__ inline unsigned short f2bf(float x) {
    unsigned int b = __float_as_uint(x);
    unsigned int r = (b + 0x7FFFu + ((b >> 16) & 1u)) >> 16;  // RNE
    return (unsigned short)r;
}
__device__ inline float bf2f(unsigned short u) {
    return __uint_as_float(((unsigned int)u) << 16);
}

// ---------------- prep: transpose weights to [N][K] bf16, zero-padded ----------------
__global__ __launch_bounds__(256) void k_prep(const float* __restrict__ W1,
                                              const float* __restrict__ W2,
                                              const float* __restrict__ W3,
                                              unsigned short* __restrict__ W1t,
                                              unsigned short* __restrict__ W2t,
                                              unsigned short* __restrict__ W3t) {
    const int idx = blockIdx.x * 256 + threadIdx.x;  // [0, 131072)
    {   // W1t[n][k], n<128, k<1024 ; W1 is [1000][128]
        const int n = idx >> 10, k = idx & 1023;
        W1t[idx] = (k < CDIM) ? f2bf(W1[(size_t)k * HDIM + n]) : (unsigned short)0;
    }
    {   // W3t[n][k], n<1024, k<128 ; W3 is [128][1000]
        const int n = idx >> 7, k = idx & 127;
        W3t[idx] = (n < CDIM) ? f2bf(W3[(size_t)k * CDIM + n]) : (unsigned short)0;
    }
    if (idx < 16384) {  // W2t[n][k], 128x128 ; W2 is [128][128]
        const int n = idx >> 7, k = idx & 127;
        W2t[idx] = f2bf(W2[(size_t)k * HDIM + n]);
    }
}

// ---------------- softmax: one wave per row, write bf16 prob (padded to 1024) --------
__global__ __launch_bounds__(256) void k_softmax(const float* __restrict__ logits,
                                                 unsigned short* __restrict__ prob) {
    const int wv = threadIdx.x >> 6, lane = threadIdx.x & 63;
    const int row = (blockIdx.x << 2) + wv;
    const int base = lane << 4;
    const float* lrow = logits + (size_t)row * CDIM;
    float lg[16];
#pragma unroll
    for (int q = 0; q < 4; ++q) {
        const int c = base + (q << 2);
        if (c < CDIM) {
            const float4 v4 = *reinterpret_cast<const float4*>(lrow + c);
            lg[q * 4] = v4.x; lg[q * 4 + 1] = v4.y; lg[q * 4 + 2] = v4.z; lg[q * 4 + 3] = v4.w;
        } else {
            lg[q * 4] = lg[q * 4 + 1] = lg[q * 4 + 2] = lg[q * 4 + 3] = -INFINITY;
        }
    }
    float mx = lg[0];
#pragma unroll
    for (int e = 1; e < 16; ++e) mx = fmaxf(mx, lg[e]);
#pragma unroll
    for (int off = 32; off >= 1; off >>= 1) mx = fmaxf(mx, __shfl_xor(mx, off));
    float p[16], s = 0.f;
#pragma unroll
    for (int e = 0; e < 16; ++e) { p[e] = __expf(lg[e] - mx); s += p[e]; }
#pragma unroll
    for (int off = 32; off >= 1; off >>= 1) s += __shfl_xor(s, off);
    const float inv = 1.f / s;
    unsigned int w[8];
#pragma unroll
    for (int i = 0; i < 8; ++i) {
        const unsigned int lo = f2bf(p[2 * i] * inv);
        const unsigned int hi = f2bf(p[2 * i + 1] * inv);
        w[i] = lo | (hi << 16);
    }
    uint4 o0, o1;
    o0.x = w[0]; o0.y = w[1]; o0.z = w[2]; o0.w = w[3];
    o1.x = w[4]; o1.y = w[5]; o1.z = w[6]; o1.w = w[7];
    uint4* dst = reinterpret_cast<uint4*>(prob + (size_t)row * CPAD + base);
    dst[0] = o0; dst[1] = o1;
}

// ---------------- GEMM: C[M,N] = epi(A[M,K] @ Bt[N,K]^T + bias) ----------------------
// 512 threads = 8 waves (4m x 2n), block tile 128x128, BK=64, XOR-swizzled LDS chunks.
// EPI 0: relu(v + bias), all cols. EPI 1: sigmoid(v+bias) except col nlimit-1 raw;
//        stores only n < nlimit (compact ldo).
template <int EPI>
__global__ __launch_bounds__(512) void k_gemm(const unsigned short* __restrict__ A, int lda,
                                              const unsigned short* __restrict__ Bt, int ldb,
                                              const float* __restrict__ bias,
                                              unsigned short* __restrict__ outp, int ldo,
                                              int K, int nlimit) {
    __shared__ uint4 As[128 * 8];
    __shared__ uint4 Bs[128 * 8];
    const int tid = threadIdx.x;
    const int bm = blockIdx.x, bn = blockIdx.y;
    const int lane = tid & 63, w = tid >> 6;
    const int wm = (w >> 1) << 5;
    const int wn = (w & 1) << 6;
    const int l15 = lane & 15, l4 = lane >> 4;
    f32x4 acc[2][4] = {};

    for (int k0 = 0; k0 < K; k0 += 64) {
        __syncthreads();
#pragma unroll
        for (int i = 0; i < 2; ++i) {
            const int cid = tid + (i << 9);
            const int r = cid >> 3, c = cid & 7;
            As[(r << 3) + (c ^ (r & 7))] =
                *reinterpret_cast<const uint4*>(A + (size_t)(bm * 128 + r) * lda + k0 + (c << 3));
            Bs[(r << 3) + (c ^ (r & 7))] =
                *reinterpret_cast<const uint4*>(Bt + (size_t)(bn * 128 + r) * ldb + k0 + (c << 3));
        }
        __syncthreads();
#pragma unroll
        for (int kk = 0; kk < 2; ++kk) {
            short8 a[2], b[4];
#pragma unroll
            for (int mf = 0; mf < 2; ++mf) {
                const int r = wm + (mf << 4) + l15;
                a[mf] = *reinterpret_cast<const short8*>(&As[(r << 3) + (((kk << 2) + l4) ^ (r & 7))]);
            }
#pragma unroll
            for (int nf = 0; nf < 4; ++nf) {
                const int r = wn + (nf << 4) + l15;
                b[nf] = *reinterpret_cast<const short8*>(&Bs[(r << 3) + (((kk << 2) + l4) ^ (r & 7))]);
            }
#pragma unroll
            for (int mf = 0; mf < 2; ++mf)
#pragma unroll
                for (int nf = 0; nf < 4; ++nf)
                    acc[mf][nf] = __builtin_amdgcn_mfma_f32_16x16x32_bf16(a[mf], b[nf], acc[mf][nf], 0, 0, 0);
        }
    }
#pragma unroll
    for (int mf = 0; mf < 2; ++mf) {
#pragma unroll
        for (int nf = 0; nf < 4; ++nf) {
            const int n = (bn << 7) + wn + (nf << 4) + l15;
            if (EPI == 1 && n >= nlimit) continue;   // compact output: skip pad cols
            const float bv = bias[n];
#pragma unroll
            for (int r = 0; r < 4; ++r) {
                const int m = (bm << 7) + wm + (mf << 4) + (l4 << 2) + r;
                float v = acc[mf][nf][r] + bv;
                if (EPI == 0) {
                    v = fmaxf(v, 0.f);
                } else {
                    if (n != nlimit - 1) v = 1.f / (1.f + __expf(-v));
                }
                outp[(size_t)m * ldo + n] = f2bf(v);
            }
        }
    }
}

// ---------------- sort + finish: counting sort v6, one wave per row --------------------
// 11-bit monotone key; single atomic pass (return = stable in-bucket offset);
// suffix-scan; rank = start[key] + offset.
// LDS v6: bijective SWZ chunk-swizzle -> streaming phases (zero / scan r+w /
// sorted-read / Sarr-write) are balanced ds_read/write_b128 (4 instrs each, 8cyc),
// random phases (atomic, rank-read, scatter, gather) are b32. 84 LDS instrs/wave
// vs 144 all-b32 in v5 -> halves LDS-pipe issue time (the measured bottleneck).
// One 1024-word region per wave, phase images overwrite dead predecessors;
// all ordering within-wave -> zero barriers.
__global__ __launch_bounds__(256) void k_sortfinish(const float* __restrict__ logits,
                                                    const unsigned short* __restrict__ cal,
                                                    float* __restrict__ out) {
    __shared__ unsigned int shm[4 * 1024];
    const int wv = threadIdx.x >> 6, lane = threadIdx.x & 63;
    const int row = (blockIdx.x << 2) + wv;
    unsigned int* sm = &shm[wv << 10];
    const int base = lane << 4;

    // swizzled bases of this lane's 4 blocked chunks (words base+4j .. +3)
    int cb[4];
#pragma unroll
    for (int j = 0; j < 4; ++j) { const int wd = base + (j << 2); cb[j] = SWZ(wd); }

    // zero histogram (4 x b128, covers all 1024 words across the wave)
    {
        uint4 z; z.x = 0; z.y = 0; z.z = 0; z.w = 0;
#pragma unroll
        for (int j = 0; j < 4; ++j) *reinterpret_cast<uint4*>(&sm[cb[j]]) = z;
    }

    // ---- load logits + hoist cal row (compact ldo = CDIM; 2000B rows are 16B-aligned)
    const float* lrow = logits + (size_t)row * CDIM;
    float lg[16];
#pragma unroll
    for (int q = 0; q < 4; ++q) {
        const int c = base + (q << 2);
        if (c < CDIM) {
            const float4 v4 = *reinterpret_cast<const float4*>(lrow + c);
            lg[q * 4] = v4.x; lg[q * 4 + 1] = v4.y; lg[q * 4 + 2] = v4.z; lg[q * 4 + 3] = v4.w;
        } else {
            lg[q * 4] = lg[q * 4 + 1] = lg[q * 4 + 2] = lg[q * 4 + 3] = -INFINITY;
        }
    }
    const unsigned short* crow = cal + (size_t)row * CDIM + base;
    const uint4 c0v = *reinterpret_cast<const uint4*>(crow);      // cols >= 1000 overread
    const uint4 c1v = *reinterpret_cast<const uint4*>(crow + 8);  // into next row: unused

    // ---- softmax (fp32, inline) ----
    float mx = lg[0];
#pragma unroll
    for (int e = 1; e < 16; ++e) mx = fmaxf(mx, lg[e]);
#pragma unroll
    for (int off = 32; off >= 1; off >>= 1) mx = fmaxf(mx, __shfl_xor(mx, off));
    float p[16], s = 0.f;
#pragma unroll
    for (int e = 0; e < 16; ++e) { p[e] = __expf(lg[e] - mx); s += p[e]; }
#pragma unroll
    for (int off = 32; off >= 1; off >>= 1) s += __shfl_xor(s, off);
    const float inv = 1.f / s;
#pragma unroll
    for (int e = 0; e < 16; ++e) p[e] *= inv;

    // ---- single atomic pass: histogram count + stable in-bucket offset ----
    unsigned int offv[16]; int swk[16];
#pragma unroll
    for (int e = 0; e < 16; ++e) {
        const unsigned int key = __float_as_uint(p[e]) >> 20;  // 11-bit monotone, <= 1016
        swk[e] = SWZ((int)key);
        offv[e] = (base + e < CDIM) ? atomicAdd(&sm[swk[e]], 1u) : 0u;
    }

    // ---- bucket suffix-scan: start[b] = sum_{b' > b} cnt[b'] (4 x b128 r/w) ----
    {
        unsigned int c16[16];
#pragma unroll
        for (int j = 0; j < 4; ++j) {
            const uint4 v4 = *reinterpret_cast<const uint4*>(&sm[cb[j]]);
            c16[4 * j] = v4.x; c16[4 * j + 1] = v4.y; c16[4 * j + 2] = v4.z; c16[4 * j + 3] = v4.w;
        }
        unsigned int lsum = 0;
#pragma unroll
        for (int e = 0; e < 16; ++e) lsum += c16[e];
        unsigned int suf = lsum;
#pragma unroll
        for (int off = 1; off < 64; off <<= 1) {
            const unsigned int u = __shfl_down(suf, off);
            if (lane + off < 64) suf += u;
        }
        unsigned int run = suf - lsum;  // sum over lanes > this lane
        unsigned int stv[16];
#pragma unroll
        for (int e = 15; e >= 0; --e) { stv[e] = run; run += c16[e]; }
#pragma unroll
        for (int j = 0; j < 4; ++j) {
            uint4 v4;
            v4.x = stv[4 * j]; v4.y = stv[4 * j + 1]; v4.z = stv[4 * j + 2]; v4.w = stv[4 * j + 3];
            *reinterpret_cast<uint4*>(&sm[cb[j]]) = v4;
        }
    }

    // ---- rank = start[key] + offset; precompute swizzled rank addr (reused twice) ----
    int swr[16];
#pragma unroll
    for (int e = 0; e < 16; ++e) {
        const int rk = (base + e < CDIM) ? (int)(sm[swk[e]] + offv[e]) : 1023;
        swr[e] = SWZ(rk);
    }

    // ---- scatter full-precision probs to rank order (start table dead) ----
#pragma unroll
    for (int e = 0; e < 16; ++e)
        if (base + e < CDIM) sm[swr[e]] = __float_as_uint(p[e]);

    // ---- sorted-prob blocked read (4 x b128) ----
    float sp[16];
#pragma unroll
    for (int j = 0; j < 4; ++j) {
        const uint4 v4 = *reinterpret_cast<const uint4*>(&sm[cb[j]]);
        sp[4 * j] = __uint_as_float(v4.x); sp[4 * j + 1] = __uint_as_float(v4.y);
        sp[4 * j + 2] = __uint_as_float(v4.z); sp[4 * j + 3] = __uint_as_float(v4.w);
    }
    const float spn_next = __shfl_down(sp[0], 1);
    const unsigned int cw[8] = {c0v.x, c0v.y, c0v.z, c0v.w, c1v.x, c1v.y, c1v.z, c1v.w};
    float v[16];
#pragma unroll
    for (int e = 0; e < 16; ++e) {
        const int r = base + e;
        const float cv = bf2f((unsigned short)((cw[e >> 1] >> ((e & 1) * 16)) & 0xFFFFu));
        const float spn = (e < 15) ? sp[e + 1] : spn_next;
        float val;
        if (r < CDIM - 1) val = (sp[e] - spn) * cv;
        else if (r == CDIM - 1) val = cv;
        else val = 0.f;
        v[e] = val;
    }
    // suffix sum over rank space
    float lsuf[16], run = 0.f;
#pragma unroll
    for (int e = 15; e >= 0; --e) { run += v[e]; lsuf[e] = run; }
    float pi = run;
#pragma unroll
    for (int off = 1; off < 64; off <<= 1) {
        const float u = __shfl_up(pi, off);
        if (lane >= off) pi += u;
    }
    const float tot = __shfl(pi, 63);
    const float after = tot - pi;

    // ---- Sarr overwrites sorted probs (4 x b128), then gather by rank ----
#pragma unroll
    for (int j = 0; j < 4; ++j) {
        uint4 v4;
        v4.x = __float_as_uint(lsuf[4 * j] + after);
        v4.y = __float_as_uint(lsuf[4 * j + 1] + after);
        v4.z = __float_as_uint(lsuf[4 * j + 2] + after);
        v4.w = __float_as_uint(lsuf[4 * j + 3] + after);
        *reinterpret_cast<uint4*>(&sm[cb[j]]) = v4;
    }
    float f[16];
#pragma unroll
    for (int e = 0; e < 16; ++e) f[e] = __uint_as_float(sm[swr[e]]);
#pragma unroll
    for (int q = 0; q < 4; ++q) {
        const int c = base + (q << 2);
        if (c < CDIM) {
            float4 o;
            o.x = lg[q * 4] + f[q * 4];
            o.y = lg[q * 4 + 1] + f[q * 4 + 1];
            o.z = lg[q * 4 + 2] + f[q * 4 + 2];
            o.w = lg[q * 4 + 3] + f[q * 4 + 3];
            *reinterpret_cast<float4*>(out + (size_t)row * CDIM + c) = o;
        }
    }
}

// ---------------- host ----------------
extern "C" void kernel_launch(void* const* d_in, const int* in_sizes, int n_in,
                              void* d_out, int out_size, void* d_ws, size_t ws_size,
                              hipStream_t stream) {
    const float* logits = (const float*)d_in[0];
    const float* W1 = (const float*)d_in[1];
    const float* b1 = (const float*)d_in[2];
    const float* W2 = (const float*)d_in[3];
    const float* b2 = (const float*)d_in[4];
    const float* W3 = (const float*)d_in[5];
    const float* b3 = (const float*)d_in[6];
    float* out = (float*)d_out;

    char* ws = (char*)d_ws;
    unsigned short* prob = (unsigned short*)ws;                    // 32768*1024*2 = 64 MB
    unsigned short* h1   = (unsigned short*)(ws + 67108864);       // 8 MB
    unsigned short* h2   = (unsigned short*)(ws + 75497472);       // 8 MB
    unsigned short* W1t  = (unsigned short*)(ws + 83886080);       // 256 KB
    unsigned short* W2t  = (unsigned short*)(ws + 84148224);       // 32 KB
    unsigned short* W3t  = (unsigned short*)(ws + 84180992);       // 256 KB
    unsigned short* cal  = prob;  // reuse: prob dead after GEMM1; cal compact ldo=CDIM

    k_prep<<<512, 256, 0, stream>>>(W1, W2, W3, W1t, W2t, W3t);
    k_softmax<<<BROWS / 4, 256, 0, stream>>>(logits, prob);
    k_gemm<0><<<dim3(BROWS / 128, 1), 512, 0, stream>>>(prob, CPAD, W1t, CPAD, b1, h1, HDIM, CPAD, 0);
    k_gemm<0><<<dim3(BROWS / 128, 1), 512, 0, stream>>>(h1, HDIM, W2t, HDIM, b2, h2, HDIM, HDIM, 0);
    k_gemm<1><<<dim3(BROWS / 128, 8), 512, 0, stream>>>(h2, HDIM, W3t, HDIM, b3, cal, CDIM, HDIM, CDIM);
    k_sortfinish<<<BROWS / 4, 256, 0, stream>>>(logits, cal, out);
}